// Round 4
// baseline (301.758 us; speedup 1.0000x reference)
//
#include <hip/hip_runtime.h>

// ExpandHarmonics: N rows -> 5 harmonic candidates each.
// Outputs concatenated flat in d_out (all float32 values):
//   [0,15N)   hkl_all   (N,5,3)  ints as floats
//   [15N,20N) wavelength_all (N,5,1)
//   [20N,25N) d_all     (N,5,1)
//   [25N,30N) refl_id   (N,5,1)  ints as floats (max ~7.09e6 < 2^24, exact)
//
// R4 = R3 with the nontemporal-store type fixed (clang ext_vector_type(4)
// instead of HIP float4, which __builtin_nontemporal_store rejects).
// R3 changes: single reused 15KB LDS buffer (2-phase flush) -> 8 blocks/CU;
// gcd via 4KB constexpr lookup (|hkl| <= 12); int divides -> exact fp
// rcp+rintf; nontemporal output stores to protect the L3-resident table.

constexpr int kHmax = 60;
constexpr int kG    = 2 * kHmax + 1;     // 121
constexpr int kG3   = kG * kG * kG;      // 1,771,561
constexpr int kT    = 256;               // block size

typedef float vf4 __attribute__((ext_vector_type(4)));  // native vec for nt-store

// gcd3 lookup: index (a<<8)|(b<<4)|c for a,b,c in [0,15]. gcd(0,0,0)=0.
struct Gcd3Tab {
    unsigned char t[4096];
    constexpr Gcd3Tab() : t{} {
        for (int a = 0; a < 16; ++a)
            for (int b = 0; b < 16; ++b)
                for (int c = 0; c < 16; ++c) {
                    int x = a, y = b;
                    while (y) { int r = x % y; x = y; y = r; }
                    int u = x, z = c;
                    while (z) { int r = u % z; u = z; z = r; }
                    t[(a << 8) | (b << 4) | c] = (unsigned char)u;
                }
    }
};
__device__ __constant__ Gcd3Tab kGcd3{};

__global__ __launch_bounds__(kT) void expand_harmonics(
    const int*   __restrict__ asu_id,
    const int*   __restrict__ hkl,
    const float* __restrict__ wavelength,
    const float* __restrict__ dmin,
    const float* __restrict__ Bmat,
    const int*   __restrict__ refl_table,
    float*       __restrict__ out,
    int N)
{
#pragma clang fp contract(off)
    __shared__ float s_buf[kT * 15];   // 15 KB, reused across two phases

    const int tid   = threadIdx.x;
    const int base  = blockIdx.x * kT;
    const int i     = base + tid;
    const int valid = min(kT, N - base);

    float wlv[5], dv[5], ridv[5];      // phase-B payload held in registers

    if (i < N) {
        int asu = asu_id[i];
        int h = hkl[3 * i + 0];
        int k = hkl[3 * i + 1];
        int l = hkl[3 * i + 2];
        float wl = wavelength[i];
        bool mask = (h | k | l) != 0;

        int a = h < 0 ? -h : h;        // |hkl| <= 12 < 16
        int b = k < 0 ? -k : k;
        int c = l < 0 ? -l : l;
        int n = kGcd3.t[(a << 8) | (b << 4) | c];
        int n_safe = n > 1 ? n : 1;

        // exact integer division via fp (quotients are exact small ints)
        float rcp_n = 1.0f / (float)n_safe;
        int h0 = (int)rintf((float)h * rcp_n);
        int k0 = (int)rintf((float)k * rcp_n);
        int l0 = (int)rintf((float)l * rcp_n);

        float wl0 = wl * (float)n_safe;
        float dmin_g = dmin[asu];

        const float* Ba = Bmat + asu * 9;
        float fh = (float)h0, fk = (float)k0, fl = (float)l0;
        // match numpy order, no FMA contraction
        float s0 = Ba[0] * fh + Ba[1] * fk + Ba[2] * fl;
        float s1 = Ba[3] * fh + Ba[4] * fk + Ba[5] * fl;
        float s2 = Ba[6] * fh + Ba[7] * fk + Ba[8] * fl;
        float nrm = sqrtf(s0 * s0 + s1 * s1 + s2 * s2);
        float d0 = 1.0f / fmaxf(nrm, 1e-6f);

        float n_max = fminf(floorf(d0 / dmin_g), floorf(wl0 / 0.95f));
        float n_min = floorf(wl0 / 1.25f) + 1.0f;

        const int tb = asu * kG3;
        #pragma unroll
        for (int j = 0; j < 5; ++j) {
            float njf = n_min + (float)j;
            if (njf > n_max) njf = 0.0f;
            int nj = (int)njf;
            int ha = h0 * nj, ka = k0 * nj, la = l0 * nj;
            int i0 = ha + kHmax, i1 = ka + kHmax, i2 = la + kHmax;
            int rid = -1;
            if ((unsigned)i0 < (unsigned)kG &&
                (unsigned)i1 < (unsigned)kG &&
                (unsigned)i2 < (unsigned)kG) {
                rid = refl_table[tb + i0 * (kG * kG) + i1 * kG + i2];
            }
            bool absent = rid < 0;
            if (absent) { ha = 0; ka = 0; la = 0; }
            float n_inv  = absent ? 0.0f : (1.0f / fmaxf((float)nj, 1e-6f));
            float d_all  = d0 * n_inv;
            float wl_all = wl0 * n_inv;
            float ridf   = (float)rid;
            if (!mask) { ha = 0; ka = 0; la = 0; d_all = 0.0f; wl_all = 0.0f; ridf = 0.0f; }

            int rb = tid * 15 + j * 3;
            s_buf[rb + 0] = (float)ha;
            s_buf[rb + 1] = (float)ka;
            s_buf[rb + 2] = (float)la;
            wlv[j] = wl_all;
            dv[j]  = d_all;
            ridv[j] = ridf;
        }
    }

    __syncthreads();

    const bool vec_ok = (valid == kT) && ((N & 3) == 0);  // 16B alignment of 15N/5N bases
    const long long oh = (long long)base * 15;

    if (vec_ok) {
        vf4* g = (vf4*)(out + oh);
        const vf4* s = (const vf4*)s_buf;                  // 960 vf4
        #pragma unroll
        for (int r = 0; r < 4; ++r) {
            int idx = r * kT + tid;
            if (idx < 960) __builtin_nontemporal_store(s[idx], g + idx);
        }
    } else {
        for (int idx = tid; idx < valid * 15; idx += kT) out[oh + idx] = s_buf[idx];
    }

    __syncthreads();   // phase A stores done before LDS reuse

    if (i < N) {
        #pragma unroll
        for (int j = 0; j < 5; ++j) {
            s_buf[tid * 5 + j]            = wlv[j];
            s_buf[kT * 5 + tid * 5 + j]   = dv[j];
            s_buf[kT * 10 + tid * 5 + j]  = ridv[j];
        }
    }

    __syncthreads();

    const long long owl = (long long)15 * N + (long long)base * 5;
    const long long od  = (long long)20 * N + (long long)base * 5;
    const long long oid = (long long)25 * N + (long long)base * 5;

    if (vec_ok) {
        const vf4* s = (const vf4*)s_buf;                  // 3 x 320 vf4
        vf4* gw = (vf4*)(out + owl);
        vf4* gd = (vf4*)(out + od);
        vf4* gi = (vf4*)(out + oid);
        #pragma unroll
        for (int r = 0; r < 2; ++r) {
            int idx = r * kT + tid;
            if (idx < 320) {
                __builtin_nontemporal_store(s[idx],       gw + idx);
                __builtin_nontemporal_store(s[320 + idx], gd + idx);
                __builtin_nontemporal_store(s[640 + idx], gi + idx);
            }
        }
    } else {
        for (int idx = tid; idx < valid * 5; idx += kT) {
            out[owl + idx] = s_buf[idx];
            out[od  + idx] = s_buf[kT * 5 + idx];
            out[oid + idx] = s_buf[kT * 10 + idx];
        }
    }
}

extern "C" void kernel_launch(void* const* d_in, const int* in_sizes, int n_in,
                              void* d_out, int out_size, void* d_ws, size_t ws_size,
                              hipStream_t stream) {
    const int*   asu_id = (const int*)d_in[0];
    const int*   hkl    = (const int*)d_in[1];
    const float* wl     = (const float*)d_in[2];
    const float* dmin   = (const float*)d_in[3];
    const float* B      = (const float*)d_in[4];
    const int*   refl   = (const int*)d_in[5];
    float* out = (float*)d_out;
    int N = in_sizes[0];  // asu_id is (N,1)

    int blocks = (N + kT - 1) / kT;
    hipLaunchKernelGGL(expand_harmonics, dim3(blocks), dim3(kT), 0, stream,
                       asu_id, hkl, wl, dmin, B, refl, out, N);
}

// Round 5
// 297.720 us; speedup vs baseline: 1.0136x; 1.0136x over previous
//
#include <hip/hip_runtime.h>

// ExpandHarmonics: N rows -> 5 harmonic candidates each.
// Outputs concatenated flat in d_out (all float32 values):
//   [0,15N)   hkl_all   (N,5,3)  ints as floats
//   [15N,20N) wavelength_all (N,5,1)
//   [20N,25N) d_all     (N,5,1)
//   [25N,30N) refl_id   (N,5,1)  ints as floats (max ~7.09e6 < 2^24, exact)
//
// R5: single-barrier structure (30KB LDS, one __syncthreads BEFORE any global
// store -> no vmcnt store-drain barriers), gcd via 4KB constexpr LUT, exact
// fp division, nontemporal vf4 output stores, and gather-skip: when nj==0
// (harmonic out of window) or hkl==0, the reference looks up the table center
// which setup unconditionally sets to -1 -> skip the load, rid=-1. Cuts ~50%
// of the 10M random table gathers.

constexpr int kHmax = 60;
constexpr int kG    = 2 * kHmax + 1;     // 121
constexpr int kG3   = kG * kG * kG;      // 1,771,561
constexpr int kT    = 256;               // block size

typedef float vf4 __attribute__((ext_vector_type(4)));  // native vec for nt-store

// gcd3 lookup: index (a<<8)|(b<<4)|c for a,b,c in [0,15]. gcd(0,0,0)=0.
struct Gcd3Tab {
    unsigned char t[4096];
    constexpr Gcd3Tab() : t{} {
        for (int a = 0; a < 16; ++a)
            for (int b = 0; b < 16; ++b)
                for (int c = 0; c < 16; ++c) {
                    int x = a, y = b;
                    while (y) { int r = x % y; x = y; y = r; }
                    int u = x, z = c;
                    while (z) { int r = u % z; u = z; z = r; }
                    t[(a << 8) | (b << 4) | c] = (unsigned char)u;
                }
    }
};
__device__ __constant__ Gcd3Tab kGcd3{};

__global__ __launch_bounds__(kT) void expand_harmonics(
    const int*   __restrict__ asu_id,
    const int*   __restrict__ hkl,
    const float* __restrict__ wavelength,
    const float* __restrict__ dmin,
    const float* __restrict__ Bmat,
    const int*   __restrict__ refl_table,
    float*       __restrict__ out,
    int N)
{
#pragma clang fp contract(off)
    __shared__ float s_hkl[kT * 15];    // 15 KB
    __shared__ float s_rest[kT * 15];   // wl | d | id, 5KB each

    const int tid   = threadIdx.x;
    const int base  = blockIdx.x * kT;
    const int i     = base + tid;
    const int valid = min(kT, N - base);

    if (i < N) {
        int asu = asu_id[i];
        int h = hkl[3 * i + 0];
        int k = hkl[3 * i + 1];
        int l = hkl[3 * i + 2];
        float wl = wavelength[i];
        bool mask = (h | k | l) != 0;

        int a = h < 0 ? -h : h;        // |hkl| <= 12 < 16
        int b = k < 0 ? -k : k;
        int c = l < 0 ? -l : l;
        int n = kGcd3.t[(a << 8) | (b << 4) | c];
        int n_safe = n > 1 ? n : 1;

        // exact integer division via fp (quotients are exact small ints)
        float rcp_n = 1.0f / (float)n_safe;
        int h0 = (int)rintf((float)h * rcp_n);
        int k0 = (int)rintf((float)k * rcp_n);
        int l0 = (int)rintf((float)l * rcp_n);

        float wl0 = wl * (float)n_safe;
        float dmin_g = dmin[asu];

        const float* Ba = Bmat + asu * 9;
        float fh = (float)h0, fk = (float)k0, fl = (float)l0;
        // match numpy order, no FMA contraction
        float s0 = Ba[0] * fh + Ba[1] * fk + Ba[2] * fl;
        float s1 = Ba[3] * fh + Ba[4] * fk + Ba[5] * fl;
        float s2 = Ba[6] * fh + Ba[7] * fk + Ba[8] * fl;
        float nrm = sqrtf(s0 * s0 + s1 * s1 + s2 * s2);
        float d0 = 1.0f / fmaxf(nrm, 1e-6f);

        float n_max = fminf(floorf(d0 / dmin_g), floorf(wl0 / 0.95f));
        float n_min = floorf(wl0 / 1.25f) + 1.0f;

        const int tb = asu * kG3;
        #pragma unroll
        for (int j = 0; j < 5; ++j) {
            float njf = n_min + (float)j;
            if (njf > n_max) njf = 0.0f;
            int nj = (int)njf;
            int ha = h0 * nj, ka = k0 * nj, la = l0 * nj;
            int i0 = ha + kHmax, i1 = ka + kHmax, i2 = la + kHmax;
            // Gather-skip: nj==0 or hkl==0 means the reference reads the table
            // center, which setup sets to -1 unconditionally. Bounds fail -> -1.
            int rid = -1;
            bool do_load = mask && (nj != 0) &&
                           (unsigned)i0 < (unsigned)kG &&
                           (unsigned)i1 < (unsigned)kG &&
                           (unsigned)i2 < (unsigned)kG;
            if (do_load) {
                rid = refl_table[tb + i0 * (kG * kG) + i1 * kG + i2];
            }
            bool absent = rid < 0;
            if (absent) { ha = 0; ka = 0; la = 0; }
            float n_inv  = absent ? 0.0f : (1.0f / fmaxf((float)nj, 1e-6f));
            float d_all  = d0 * n_inv;
            float wl_all = wl0 * n_inv;
            float ridf   = (float)rid;
            if (!mask) { ha = 0; ka = 0; la = 0; d_all = 0.0f; wl_all = 0.0f; ridf = 0.0f; }

            int rb = tid * 15 + j * 3;         // stride-15: 2-way bank alias, free
            s_hkl[rb + 0] = (float)ha;
            s_hkl[rb + 1] = (float)ka;
            s_hkl[rb + 2] = (float)la;
            int r5 = tid * 5 + j;              // stride-5: 2-way alias, free
            s_rest[r5]            = wl_all;
            s_rest[kT * 5 + r5]   = d_all;
            s_rest[kT * 10 + r5]  = ridf;
        }
    }

    __syncthreads();   // only LDS writes + consumed loads outstanding here

    const bool vec_ok = (valid == kT) && ((N & 3) == 0);
    const long long oh  = (long long)base * 15;
    const long long owl = (long long)15 * N + (long long)base * 5;
    const long long od  = (long long)20 * N + (long long)base * 5;
    const long long oid = (long long)25 * N + (long long)base * 5;

    if (vec_ok) {
        const vf4* sh = (const vf4*)s_hkl;     // 960 vf4
        const vf4* sr = (const vf4*)s_rest;    // 3 x 320 vf4
        vf4* gh = (vf4*)(out + oh);
        vf4* gw = (vf4*)(out + owl);
        vf4* gd = (vf4*)(out + od);
        vf4* gi = (vf4*)(out + oid);
        #pragma unroll
        for (int r = 0; r < 4; ++r) {
            int idx = r * kT + tid;
            if (idx < 960) __builtin_nontemporal_store(sh[idx], gh + idx);
        }
        #pragma unroll
        for (int r = 0; r < 2; ++r) {
            int idx = r * kT + tid;
            if (idx < 320) {
                __builtin_nontemporal_store(sr[idx],       gw + idx);
                __builtin_nontemporal_store(sr[320 + idx], gd + idx);
                __builtin_nontemporal_store(sr[640 + idx], gi + idx);
            }
        }
    } else {
        for (int idx = tid; idx < valid * 15; idx += kT) out[oh + idx] = s_hkl[idx];
        for (int idx = tid; idx < valid * 5;  idx += kT) {
            out[owl + idx] = s_rest[idx];
            out[od  + idx] = s_rest[kT * 5 + idx];
            out[oid + idx] = s_rest[kT * 10 + idx];
        }
    }
}

extern "C" void kernel_launch(void* const* d_in, const int* in_sizes, int n_in,
                              void* d_out, int out_size, void* d_ws, size_t ws_size,
                              hipStream_t stream) {
    const int*   asu_id = (const int*)d_in[0];
    const int*   hkl    = (const int*)d_in[1];
    const float* wl     = (const float*)d_in[2];
    const float* dmin   = (const float*)d_in[3];
    const float* B      = (const float*)d_in[4];
    const int*   refl   = (const int*)d_in[5];
    float* out = (float*)d_out;
    int N = in_sizes[0];  // asu_id is (N,1)

    int blocks = (N + kT - 1) / kT;
    hipLaunchKernelGGL(expand_harmonics, dim3(blocks), dim3(kT), 0, stream,
                       asu_id, hkl, wl, dmin, B, refl, out, N);
}